// Round 7
// baseline (255.485 us; speedup 1.0000x reference)
//
#include <hip/hip_runtime.h>
#include <hip/hip_bf16.h>

typedef __bf16 bf16x8 __attribute__((ext_vector_type(8)));
typedef float  f32x4  __attribute__((ext_vector_type(4)));
typedef short  short8 __attribute__((ext_vector_type(8)));
typedef float  f32x4v __attribute__((ext_vector_type(4)));

#define B_SZ 4
#define N_SZ 16384
#define DIM_SZ 384
#define H_SZ 8
#define C_SZ 48
#define M_SZ 24

static constexpr float SCALE = 0.37991784282579627f;   // 48^-0.25
static constexpr float RSM   = 0.20412414523193154f;   // 1/sqrt(24)
static constexpr float EPS_V = 1e-6f;

// kvll column map (1152): [k: 0..383 | v: 384..767 | logit_q: 768..959 | logit_k: 960..1151]
// Baug rows (1280 padded): [Wk | Wv | Wlq | Wlk | pad 1152..1279]

// ---------------- async global->LDS (16B per lane) ----------------
__device__ __forceinline__ void gld_lds16(void* lds, const void* g) {
  __builtin_amdgcn_global_load_lds(
      (const __attribute__((address_space(1))) unsigned int*)g,
      (__attribute__((address_space(3))) unsigned int*)lds, 16, 0, 0);
}

__device__ __forceinline__ float bf2f(short s) {
  union { unsigned u; float f; } cv;
  cv.u = ((unsigned)(unsigned short)s) << 16;
  return cv.f;
}
__device__ __forceinline__ short f2bf_s(float f) {
  const __bf16 b = (__bf16)f;
  return __builtin_bit_cast(short, b);
}
__device__ __forceinline__ f32x4 MF(bf16x8 a, bf16x8 b, f32x4 c) {
  return __builtin_amdgcn_mfma_f32_16x16x32_bf16(a, b, c, 0, 0, 0);
}
__device__ __forceinline__ void bar_lgkm() {
  __builtin_amdgcn_s_barrier();
  asm volatile("s_waitcnt lgkmcnt(0)" ::: "memory");
  __builtin_amdgcn_sched_barrier(0);
}
__device__ __forceinline__ void bar2() {
  __builtin_amdgcn_s_barrier();
  __builtin_amdgcn_sched_barrier(0);
}
__device__ __forceinline__ void mfmaq(f32x4 (&ac)[4][2],
                                      const bf16x8 (&a)[4][2],
                                      const bf16x8 (&b)[2][2]) {
  __builtin_amdgcn_s_setprio(1);
  #pragma unroll
  for (int mf = 0; mf < 4; ++mf) {
    ac[mf][0] = MF(a[mf][0], b[0][0], ac[mf][0]);
    ac[mf][0] = MF(a[mf][1], b[0][1], ac[mf][0]);
    ac[mf][1] = MF(a[mf][0], b[1][0], ac[mf][1]);
    ac[mf][1] = MF(a[mf][1], b[1][1], ac[mf][1]);
  }
  __builtin_amdgcn_s_setprio(0);
}

// ============ 8-phase 256x256 bf16 GEMM (m201 port), C = A @ B^T ===========
// 512 thr = 8 waves (2M x 4N); per phase: wave computes 64x32 of one 128x128
// C-quadrant (16 MFMA). 2 LDS bufs x 64KB; 1 half-tile staged per phase;
// vmcnt(4) at p3/p7; XOR-swizzled LDS; nt must be EVEN. Writes bf16, cols<Nw.
__global__ __launch_bounds__(512, 2) void gemm8p(
    const __bf16* __restrict__ A, const __bf16* __restrict__ Bm,
    __bf16* __restrict__ Cout, int Nw, int K) {
  extern __shared__ __align__(16) char lds[];   // 2 * 65536
  const int t    = threadIdx.x;
  const int lane = t & 63;
  const int wid  = t >> 6;
  const int wm   = wid >> 2;          // 0..1
  const int wn   = wid & 3;           // 0..3
  const int l15  = lane & 15;
  const int kgq  = lane >> 4;

  // bijective XCD chunk swizzle (m204)
  const int gx   = gridDim.x;
  const int nwg  = gx * gridDim.y;
  const int orig = blockIdx.y * gx + blockIdx.x;
  const int qq   = nwg >> 3, rr = nwg & 7;
  const int xcd  = orig & 7, pos = orig >> 3;
  const int id   = (xcd < rr ? xcd*(qq+1) : rr*(qq+1) + (xcd-rr)*qq) + pos;
  const int row0 = (id / gx) * 256, col0 = (id % gx) * 256;

  const int nt = K >> 6;              // K-tiles (even)
  const int sg = (t & 7) ^ ((t >> 3) & 7);

  // stage one half-tile (128 rows x 64 cols = 2 loads/thread)
  auto stageh = [&](int k, int isB, int half) {
    if (k >= nt) return;
    char* base = lds + (k & 1) * 65536 + isB * 32768;
    const __bf16* src = isB ? (Bm + (size_t)col0 * K) : (A + (size_t)row0 * K);
    #pragma unroll
    for (int i = 0; i < 2; ++i) {
      const int r = half*128 + i*64 + (t >> 3);
      gld_lds16(base + r*128 + (t & 7)*16,
                src + (size_t)r * K + (size_t)k*64 + sg*8);
    }
  };
  auto loadA = [&](const char* buf, int qm, bf16x8 (&af)[4][2]) {
    #pragma unroll
    for (int mf = 0; mf < 4; ++mf) {
      const int r = qm*128 + wm*64 + mf*16 + l15;
      af[mf][0] = *(const bf16x8*)(buf + r*128 + ((kgq*16)      ^ ((r&7)<<4)));
      af[mf][1] = *(const bf16x8*)(buf + r*128 + ((64 + kgq*16) ^ ((r&7)<<4)));
    }
  };
  auto loadB = [&](const char* buf, int qn, bf16x8 (&bq)[2][2]) {
    #pragma unroll
    for (int nf = 0; nf < 2; ++nf) {
      const int r = qn*128 + wn*32 + nf*16 + l15;
      bq[nf][0] = *(const bf16x8*)(buf + 32768 + r*128 + ((kgq*16)      ^ ((r&7)<<4)));
      bq[nf][1] = *(const bf16x8*)(buf + 32768 + r*128 + ((64 + kgq*16) ^ ((r&7)<<4)));
    }
  };

  f32x4 acc[2][2][4][2] = {};   // [qm][qn][mf][nf]
  bf16x8 af[4][2], bq0[2][2], bq1[2][2];

  // prologue: kt0 all 4 halves + kt1.{A0,B0} = 12 loads; wait kt0 (leave 4)
  stageh(0, 0, 0); stageh(0, 1, 0); stageh(0, 0, 1); stageh(0, 1, 1);
  stageh(1, 0, 0); stageh(1, 1, 0);
  asm volatile("s_waitcnt vmcnt(4)" ::: "memory");
  __builtin_amdgcn_s_barrier();
  __builtin_amdgcn_sched_barrier(0);

  const int nIter = nt >> 1;
  for (int it = 0; it < nIter; ++it) {
    const int kt1 = 2*it + 1, kt2 = 2*it + 2, kt3 = 2*it + 3;
    char* b0 = lds;
    char* b1 = lds + 65536;
    const bool lastIt = (it == nIter - 1);

    // p0: quad(0,0) of kt0
    loadA(b0, 0, af); loadB(b0, 0, bq0);
    stageh(kt1, 0, 1);                       // kt1.A1 -> buf1 (last read prev p7)
    bar_lgkm(); mfmaq(acc[0][0], af, bq0); bar2();
    // p1: quad(0,1)
    loadB(b0, 1, bq1);
    stageh(kt1, 1, 1);                       // kt1.B1
    bar_lgkm(); mfmaq(acc[0][1], af, bq1); bar2();
    // p2: quad(1,0)
    loadA(b0, 1, af);
    stageh(kt2, 0, 0);                       // kt2.A0 (buf0.A0 free since p2)
    bar_lgkm(); mfmaq(acc[1][0], af, bq0); bar2();
    // p3: quad(1,1); vmcnt covers kt1 complete
    stageh(kt2, 1, 0);                       // kt2.B0
    if (lastIt) asm volatile("s_waitcnt vmcnt(0)" ::: "memory");
    else        asm volatile("s_waitcnt vmcnt(4)" ::: "memory");
    __builtin_amdgcn_s_barrier();
    __builtin_amdgcn_sched_barrier(0);
    mfmaq(acc[1][1], af, bq1); bar2();
    // p4: quad(0,0) of kt1
    loadA(b1, 0, af); loadB(b1, 0, bq0);
    stageh(kt2, 0, 1);                       // kt2.A1
    bar_lgkm(); mfmaq(acc[0][0], af, bq0); bar2();
    // p5: quad(0,1)
    loadB(b1, 1, bq1);
    stageh(kt2, 1, 1);                       // kt2.B1
    bar_lgkm(); mfmaq(acc[0][1], af, bq1); bar2();
    // p6: quad(1,0)
    loadA(b1, 1, af);
    stageh(kt3, 0, 0);                       // kt3.A0
    bar_lgkm(); mfmaq(acc[1][0], af, bq0); bar2();
    // p7: quad(1,1); vmcnt covers kt2 complete (for next iter p0 reads)
    stageh(kt3, 1, 0);                       // kt3.B0
    if (!lastIt) asm volatile("s_waitcnt vmcnt(4)" ::: "memory");
    __builtin_amdgcn_s_barrier();
    __builtin_amdgcn_sched_barrier(0);
    mfmaq(acc[1][1], af, bq1); bar2();
  }

  // epilogue: C/D col = l15 (B-side), row = (lane>>4)*4 + j (A-side)
  const int cr = (lane >> 4) << 2;
  #pragma unroll
  for (int qm = 0; qm < 2; ++qm)
    #pragma unroll
    for (int qn = 0; qn < 2; ++qn)
      #pragma unroll
      for (int mf = 0; mf < 4; ++mf)
        #pragma unroll
        for (int nf = 0; nf < 2; ++nf) {
          const int col = col0 + qn*128 + wn*32 + nf*16 + l15;
          if (col < Nw) {
            #pragma unroll
            for (int j = 0; j < 4; ++j) {
              const int row = row0 + qm*128 + wm*64 + mf*16 + cr + j;
              Cout[(size_t)row * Nw + col] = (__bf16)acc[qm][qn][mf][nf][j];
            }
          }
        }
}

// ============ 2-block/CU pipelined bf16 GEMM (round-6, for K=192) ==========
template<int EPI>
__global__ __launch_bounds__(256, 2) void gemm2b(
    const __bf16* __restrict__ A, const __bf16* __restrict__ Bm,
    void* __restrict__ Cout, const float* __restrict__ bias,
    int M, int Nw, int K,
    size_t aSlice, size_t bSlice, size_t cSlice) {
  extern __shared__ __align__(16) char lds[];   // 2 * 32768
  const int t    = threadIdx.x;
  const int lane = t & 63;
  const int wid  = t >> 6;
  const int wm   = wid >> 1;
  const int wn   = wid & 1;
  const int l15  = lane & 15;
  const int kgq  = lane >> 4;

  const int bz = blockIdx.z;
  const __bf16* Ab = A  + (size_t)bz * aSlice;
  const __bf16* Bb = Bm + (size_t)bz * bSlice;

  const int gx   = gridDim.x;
  const int nwg  = gx * gridDim.y;
  const int orig = blockIdx.y * gx + blockIdx.x;
  const int qq   = nwg >> 3, rr = nwg & 7;
  const int xcd  = orig & 7, pos = orig >> 3;
  const int id   = (xcd < rr ? xcd*(qq+1) : rr*(qq+1) + (xcd-rr)*qq) + pos;
  const int row0 = (id / gx) * 128, col0 = (id % gx) * 128;

  const int nt = K >> 6;
  const int sg = (t & 7) ^ ((t >> 3) & 7);

  auto stage = [&](int kt) {
    char* buf = lds + (kt & 1) * 32768;
    const size_t kofs = (size_t)kt * 64 + sg * 8;
    #pragma unroll
    for (int i = 0; i < 4; ++i) {
      const int r = i*32 + (t >> 3);
      gld_lds16(buf + i*4096 + t*16,         Ab + (size_t)(row0 + r) * K + kofs);
      gld_lds16(buf + 16384 + i*4096 + t*16, Bb + (size_t)(col0 + r) * K + kofs);
    }
  };

  f32x4 acc[4][4] = {};
  stage(0);

  for (int kt = 0; kt < nt; ++kt) {
    asm volatile("s_waitcnt vmcnt(0)" ::: "memory");
    __builtin_amdgcn_s_barrier();
    __builtin_amdgcn_sched_barrier(0);

    char* buf = lds + (kt & 1) * 32768;
    if (kt + 1 < nt) stage(kt + 1);

    bf16x8 bfr[4][2];
    #pragma unroll
    for (int ni = 0; ni < 4; ++ni) {
      const int brow = wn*64 + ni*16 + l15;
      #pragma unroll
      for (int kk = 0; kk < 2; ++kk)
        bfr[ni][kk] = *(const bf16x8*)(buf + 16384 + brow*128
                          + ((kk*64 + kgq*16) ^ ((brow & 7) << 4)));
    }
    #pragma unroll
    for (int mi = 0; mi < 4; ++mi) {
      const int arow = wm*64 + mi*16 + l15;
      const bf16x8 a0 = *(const bf16x8*)(buf + arow*128
                          + ((kgq*16)      ^ ((arow & 7) << 4)));
      const bf16x8 a1 = *(const bf16x8*)(buf + arow*128
                          + ((64 + kgq*16) ^ ((arow & 7) << 4)));
      __builtin_amdgcn_s_setprio(1);
      #pragma unroll
      for (int ni = 0; ni < 4; ++ni) {
        acc[mi][ni] = MF(a0, bfr[ni][0], acc[mi][ni]);
        acc[mi][ni] = MF(a1, bfr[ni][1], acc[mi][ni]);
      }
      __builtin_amdgcn_s_setprio(0);
    }
  }

  const int cr = (lane >> 4) << 2;
  #pragma unroll
  for (int mi = 0; mi < 4; ++mi) {
    #pragma unroll
    for (int ni = 0; ni < 4; ++ni) {
      const int col = col0 + wn*64 + ni*16 + l15;
      #pragma unroll
      for (int j = 0; j < 4; ++j) {
        const int row = row0 + wm*64 + mi*16 + cr + j;
        const float v = acc[mi][ni][j];
        if (EPI == 1) {
          ((float*)Cout + (size_t)bz*cSlice)[(size_t)row * Nw + col] = v + bias[col];
        } else {
          ((__bf16*)Cout + (size_t)bz*cSlice)[(size_t)row * Nw + col] = (__bf16)v;
        }
      }
    }
  }
}

// ---- combined log-weights: Baug rows 768..1151 = scale * (w @ qkv_w_side) --
__global__ __launch_bounds__(256) void wlog_kernel(
    const float* __restrict__ qkv_w, const float* __restrict__ w,
    __bf16* __restrict__ Baug) {
  const int idx = blockIdx.x * 256 + threadIdx.x;   // 2*192*384
  if (idx >= 2*192*384) return;
  const int d = idx % 384, rs = idx / 384;
  const int side = rs / 192, hm = rs % 192;
  const int h = hm / 24;
  const float* wr = w + (size_t)hm * 48;
  const float* qw = qkv_w + ((size_t)(side*384 + h*48)) * 384 + d;
  float acc = 0.f;
  #pragma unroll
  for (int c = 0; c < 48; ++c)
    acc += wr[c] * qw[(size_t)c * 384];
  Baug[(size_t)(768 + side*192 + hm) * 384 + d] = (__bf16)(acc * SCALE);
}

// ---------------- ktv fused: phi_k from [k|lk], MFMA ktv + ksum ----------
__global__ __launch_bounds__(256) void ktv_fused(
    const __bf16* __restrict__ kvll, float* __restrict__ ktv_f,
    float* __restrict__ ksum) {
  const int b = blockIdx.z, h = blockIdx.y, sp = blockIdx.x;
  const int t = threadIdx.x, wv = t >> 6, lane = t & 63;
  const int l15 = lane & 15, g = lane >> 4;
  const int bh = b*H_SZ + h;
  __shared__ __align__(16) __bf16 vT[4][48][40];    // [wave][c][tok]
  __shared__ __align__(16) __bf16 phiT[4][24][40];  // [wave][m][tok]
  __shared__ float red[4][1152];
  f32x4 acc[2][3] = {};
  f32x4 aks[2] = {};                 // ksum via ones-column MFMA
  const int nbase = sp*512 + wv*128;

  bf16x8 ones{};                     // B-frag: col 0 = all-ones
  if (l15 == 0)
    #pragma unroll
    for (int j = 0; j < 8; ++j) ones[j] = (__bf16)1.0f;

  for (int step = 0; step < 4; ++step) {
    const int n0 = nbase + step*32;
    #pragma unroll
    for (int it = 0; it < 3; ++it) {
      const int task = it*64 + lane;
      const int tk = task / 6, p = task % 6;
      const short8 r = *(const short8*)(kvll + ((size_t)(b*N_SZ) + n0 + tk)*1152
                                            + 384 + h*C_SZ + p*8);
      #pragma unroll
      for (int e = 0; e < 8; ++e)
        vT[wv][p*8 + e][tk] = __builtin_bit_cast(__bf16, (short)r[e]);
    }
    if (lane < 32) {
      const __bf16* row = kvll + ((size_t)(b*N_SZ) + n0 + lane)*1152 + h*C_SZ;
      float ss = 0.f;
      #pragma unroll
      for (int i = 0; i < 6; ++i) {
        const short8 r = *(const short8*)(row + i*8);
        #pragma unroll
        for (int j = 0; j < 8; ++j) { const float f = bf2f(r[j]) * SCALE; ss += f*f; }
      }
      const float hs = 0.5f * ss;
      const __bf16* lk = kvll + ((size_t)(b*N_SZ) + n0 + lane)*1152 + 960 + h*24;
      #pragma unroll
      for (int i = 0; i < 3; ++i) {
        const short8 r = *(const short8*)(lk + i*8);
        #pragma unroll
        for (int j = 0; j < 8; ++j)
          phiT[wv][i*8 + j][lane] = (__bf16)(__expf(bf2f(r[j]) - hs) * RSM);
      }
    }
    const bf16x8 a0 = *(const bf16x8*)(&phiT[wv][l15][g*8]);
    bf16x8 a1{};
    if (l15 < 8) a1 = *(const bf16x8*)(&phiT[wv][16 + l15][g*8]);
    #pragma unroll
    for (int ct = 0; ct < 3; ++ct) {
      const bf16x8 bfr = *(const bf16x8*)(&vT[wv][ct*16 + l15][g*8]);
      acc[0][ct] = MF(a0, bfr, acc[0][ct]);
      acc[1][ct] = MF(a1, bfr, acc[1][ct]);
    }
    aks[0] = MF(a0, ones, aks[0]);
    aks[1] = MF(a1, ones, aks[1]);
  }

  if (l15 == 0) {
    #pragma unroll
    for (int mt = 0; mt < 2; ++mt)
      #pragma unroll
      for (int jj = 0; jj < 4; ++jj) {
        const int m = mt*16 + g*4 + jj;
        if (m < 24) atomicAdd(&ksum[bh*24 + m], aks[mt][jj]);
      }
  }
  #pragma unroll
  for (int mt = 0; mt < 2; ++mt)
    #pragma unroll
    for (int ct = 0; ct < 3; ++ct)
      #pragma unroll
      for (int jj = 0; jj < 4; ++jj) {
        const int row = mt*16 + g*4 + jj;
        if (row < 24)
          red[wv][row*48 + ct*16 + l15] = acc[mt][ct][jj];
      }
  __syncthreads();
  for (int i = t; i < 1152; i += 256) {
    const float s = red[0][i] + red[1][i] + red[2][i] + red[3][i];
    atomicAdd(&ktv_f[bh*1152 + i], s);
  }
}

// ---- Gt[b][o][hm] = sum_c ktv[bh][m][c] * proj_w[o][48h+c]  (bf16 out) ----
__global__ __launch_bounds__(256) void gt_kernel(
    const float* __restrict__ ktv_f, const float* __restrict__ proj_w,
    __bf16* __restrict__ Gt) {
  const int idx = blockIdx.x * 256 + threadIdx.x;   // 4*384*192
  if (idx >= 4*384*192) return;
  const int hm = idx % 192, o = (idx / 192) % 384, b = idx / (192*384);
  const int h = hm / 24, m = hm % 24;
  const float* kt = ktv_f + ((size_t)(b*H_SZ + h))*1152 + m*48;
  const float* pw = proj_w + (size_t)o*384 + h*48;
  float acc = 0.f;
  #pragma unroll
  for (int c = 0; c < 48; ++c) acc += kt[c] * pw[c];
  Gt[((size_t)b*384 + o)*192 + hm] = (__bf16)acc;
}

// ---- P'[n][hm] = phi_q / D_h  (phi_q = exp(lq)*RSM; hs_q cancels) --------
__global__ __launch_bounds__(256) void pprime_kernel(
    const __bf16* __restrict__ kvll, const float* __restrict__ ksum,
    __bf16* __restrict__ Pp) {
  const int tok = blockIdx.x * 256 + threadIdx.x;
  const int b = (blockIdx.x * 256) >> 14;
  __shared__ float ksl[192];
  if (threadIdx.x < 192) ksl[threadIdx.x] = ksum[b*192 + threadIdx.x];
  __syncthreads();

  const __bf16* lq = kvll + (size_t)tok*1152 + 768;
  __bf16* po = Pp + (size_t)tok*192;
  #pragma unroll
  for (int h = 0; h < 8; ++h) {
    float ph[24];
    float d = EPS_V;
    #pragma unroll
    for (int i = 0; i < 3; ++i) {
      const short8 r = *(const short8*)(lq + h*24 + i*8);
      #pragma unroll
      for (int j = 0; j < 8; ++j) {
        const float p = __expf(bf2f(r[j])) * RSM;
        ph[i*8 + j] = p;
        d += p * ksl[h*24 + i*8 + j];
      }
    }
    const float inv = 1.0f / d;
    #pragma unroll
    for (int i = 0; i < 3; ++i) {
      short8 pk;
      #pragma unroll
      for (int j = 0; j < 8; ++j) pk[j] = f2bf_s(ph[i*8 + j] * inv);
      *(short8*)(po + h*24 + i*8) = pk;
    }
  }
}

// ---------------- fp32 -> bf16 convert ----------------
__global__ __launch_bounds__(256) void f32_to_bf16_kernel(
    const float* __restrict__ in, __bf16* __restrict__ out, int n8) {
  const int i = blockIdx.x * blockDim.x + threadIdx.x;
  if (i >= n8) return;
  const f32x4v a = *(const f32x4v*)(in + (size_t)i*8);
  const f32x4v c = *(const f32x4v*)(in + (size_t)i*8 + 4);
  short8 pk;
  #pragma unroll
  for (int j = 0; j < 4; ++j) {
    pk[j]     = f2bf_s(a[j]);
    pk[4 + j] = f2bf_s(c[j]);
  }
  *(short8*)(out + (size_t)i*8) = pk;
}

extern "C" void kernel_launch(void* const* d_in, const int* in_sizes, int n_in,
                              void* d_out, int out_size, void* d_ws, size_t ws_size,
                              hipStream_t stream) {
  (void)in_sizes; (void)n_in; (void)out_size; (void)ws_size;
  const float* x      = (const float*)d_in[0];
  const float* qkv_w  = (const float*)d_in[1];
  const float* proj_w = (const float*)d_in[2];
  const float* proj_b = (const float*)d_in[3];
  const float* w      = (const float*)d_in[4];
  float* out = (float*)d_out;

  const size_t BN_TOT = (size_t)B_SZ * N_SZ;           // 65536
  char* ws = (char*)d_ws;
  size_t off = 0;
  auto alloc = [&](size_t bytes) {
    char* p = ws + off;
    off += (bytes + 255) & ~(size_t)255;
    return p;
  };
  __bf16* x_bf  = (__bf16*)alloc(BN_TOT * DIM_SZ * 2);          // 50.3 MB
  __bf16* Baug  = (__bf16*)alloc((size_t)1280 * 384 * 2);       // 0.98 MB (padded)
  __bf16* kvll  = (__bf16*)alloc(BN_TOT * 1152 * 2);            // 151 MB
  float*  ktv_f = (float*)alloc((size_t)32 * 1152 * 4);
  float*  ksum  = (float*)alloc((size_t)32 * 24 * 4);
  __bf16* Pp    = (__bf16*)alloc(BN_TOT * 192 * 2);             // 25.2 MB
  __bf16* Gt    = (__bf16*)alloc((size_t)B_SZ * 384 * 192 * 2); // 0.6 MB

  hipMemsetAsync(ktv_f, 0, (size_t)32 * 1152 * 4, stream);
  hipMemsetAsync(ksum,  0, (size_t)32 * 24 * 4, stream);

  static const int LDS8P = 2 * 65536;    // 128 KB
  static const int LDS2B = 2 * 32768;    // 64 KB
  hipFuncSetAttribute(reinterpret_cast<const void*>(&gemm8p),
                      hipFuncAttributeMaxDynamicSharedMemorySize, LDS8P);
  hipFuncSetAttribute(reinterpret_cast<const void*>(&gemm2b<1>),
                      hipFuncAttributeMaxDynamicSharedMemorySize, LDS2B);

  // conversions + combined weights
  {
    const int n8x = (int)(BN_TOT * DIM_SZ / 8);
    f32_to_bf16_kernel<<<(n8x + 255)/256, 256, 0, stream>>>(x, x_bf, n8x);
    // Baug rows 0..767 = [Wk | Wv] (qkv_w rows 384..1151)
    const int n8kv = 768 * 384 / 8;
    f32_to_bf16_kernel<<<(n8kv + 255)/256, 256, 0, stream>>>(
        qkv_w + (size_t)384 * 384, Baug, n8kv);
    // Baug rows 768..1151 = scale * (w @ qkv_w_{q,k});  rows 1152..1279 = don't-care
    wlog_kernel<<<(2*192*384 + 255)/256, 256, 0, stream>>>(qkv_w, w, Baug);
  }

  // kvll = x @ Baug.T : [k | v | lq | lk]  (65536 x 1152(pad 1280) x 384)
  gemm8p<<<dim3(1280/256, BN_TOT/256), 512, LDS8P, stream>>>(
      x_bf, Baug, kvll, 1152, DIM_SZ);

  // ktv + ksum (phi_k from k + lk)
  ktv_fused<<<dim3(32, H_SZ, B_SZ), 256, 0, stream>>>(kvll, ktv_f, ksum);

  // Gt = ktv @ proj_w^T (per batch), P' = phi_q / D
  gt_kernel<<<(4*384*192 + 255)/256, 256, 0, stream>>>(ktv_f, proj_w, Gt);
  pprime_kernel<<<(int)(BN_TOT/256), 256, 0, stream>>>(kvll, ksum, Pp);

  // out = P' @ Gt^T + bias   (4 x [16384 x 384 x 192])
  gemm2b<1><<<dim3(384/128, N_SZ/128, B_SZ), 256, LDS2B, stream>>>(
      Pp, Gt, out, proj_b, N_SZ, 384, 192,
      (size_t)N_SZ * 192, (size_t)384 * 192, (size_t)N_SZ * 384);
}

// Round 8
// 246.324 us; speedup vs baseline: 1.0372x; 1.0372x over previous
//
#include <hip/hip_runtime.h>
#include <hip/hip_bf16.h>

typedef __bf16 bf16x8 __attribute__((ext_vector_type(8)));
typedef float  f32x4  __attribute__((ext_vector_type(4)));
typedef short  short8 __attribute__((ext_vector_type(8)));
typedef float  f32x4v __attribute__((ext_vector_type(4)));

#define B_SZ 4
#define N_SZ 16384
#define DIM_SZ 384
#define H_SZ 8
#define C_SZ 48
#define M_SZ 24

static constexpr float SCALE = 0.37991784282579627f;   // 48^-0.25
static constexpr float RSM   = 0.20412414523193154f;   // 1/sqrt(24)
static constexpr float EPS_V = 1e-6f;

// kvll column map (1152): [k: 0..383 | v: 384..767 | logit_q: 768..959 | logit_k: 960..1151]
// Baug rows:              [Wk: 0..383 | Wv: 384..767 | Wlq: 768..959 | Wlk: 960..1151]

// ---------------- async global->LDS (16B per lane) ----------------
__device__ __forceinline__ void gld_lds16(void* lds, const void* g) {
  __builtin_amdgcn_global_load_lds(
      (const __attribute__((address_space(1))) unsigned int*)g,
      (__attribute__((address_space(3))) unsigned int*)lds, 16, 0, 0);
}

__device__ __forceinline__ float bf2f(short s) {
  union { unsigned u; float f; } cv;
  cv.u = ((unsigned)(unsigned short)s) << 16;
  return cv.f;
}
__device__ __forceinline__ short f2bf_s(float f) {
  const __bf16 b = (__bf16)f;
  return __builtin_bit_cast(short, b);
}
__device__ __forceinline__ f32x4 MF(bf16x8 a, bf16x8 b, f32x4 c) {
  return __builtin_amdgcn_mfma_f32_16x16x32_bf16(a, b, c, 0, 0, 0);
}

// ============ 4-block/CU BK=32 bf16 GEMM, C = A[M][K] @ B^T[N][K] ==========
// BM=BN=128, BK=32, 256 thr = 4 waves (2x2), per-wave 64x64 (4x4 frags),
// 16 MFMA/iter. 2 LDS buffers x 16KB (A 8KB + B 8KB) = 32KB -> 4 blocks/CU
// (VGPR-capped via launch_bounds(256,4)); co-resident blocks hide the
// vmcnt(0) drain. 64B LDS rows, XOR swizzle slot^=(r&3) (4-way worst case).
// EPI 0: bf16 write. EPI 1: fp32 write + bias. blockIdx.z slices by *Slice.
template<int EPI>
__global__ __launch_bounds__(256, 4) void gemm32(
    const __bf16* __restrict__ A, const __bf16* __restrict__ Bm,
    void* __restrict__ Cout, const float* __restrict__ bias,
    int M, int Nw, int K,
    size_t aSlice, size_t bSlice, size_t cSlice) {
  extern __shared__ __align__(16) char lds[];   // 2 * 16384
  const int t    = threadIdx.x;
  const int lane = t & 63;
  const int wid  = t >> 6;
  const int wm   = wid >> 1;          // 0..1
  const int wn   = wid & 1;           // 0..1
  const int l15  = lane & 15;
  const int kgq  = lane >> 4;         // 0..3

  const int bz = blockIdx.z;
  const __bf16* Ab = A  + (size_t)bz * aSlice;
  const __bf16* Bb = Bm + (size_t)bz * bSlice;

  // bijective XCD chunk swizzle (m204), per z-slice
  const int gx   = gridDim.x;
  const int nwg  = gx * gridDim.y;
  const int orig = blockIdx.y * gx + blockIdx.x;
  const int qq   = nwg >> 3, rr = nwg & 7;
  const int xcd  = orig & 7, pos = orig >> 3;
  const int id   = (xcd < rr ? xcd*(qq+1) : rr*(qq+1) + (xcd-rr)*qq) + pos;
  const int row0 = (id / gx) * 128, col0 = (id % gx) * 128;

  const int nt = K >> 5;              // K-tiles of 32

  // staging: row r = i*64 + (t>>2), LDS slot (t&3); global slot = (t&3)^(r&3)
  const int sg8 = ((t & 3) ^ ((t >> 2) & 3)) * 8;   // element offset

  auto stage = [&](int kt) {
    char* buf = lds + (kt & 1) * 16384;
    const size_t kofs = (size_t)kt * 32 + sg8;
    #pragma unroll
    for (int i = 0; i < 2; ++i) {
      const int r = i*64 + (t >> 2);
      gld_lds16(buf + i*4096 + t*16,        Ab + (size_t)(row0 + r) * K + kofs);
      gld_lds16(buf + 8192 + i*4096 + t*16, Bb + (size_t)(col0 + r) * K + kofs);
    }
  };

  f32x4 acc[4][4] = {};
  stage(0);

  for (int kt = 0; kt < nt; ++kt) {
    asm volatile("s_waitcnt vmcnt(0)" ::: "memory");
    __builtin_amdgcn_s_barrier();
    __builtin_amdgcn_sched_barrier(0);

    char* buf = lds + (kt & 1) * 16384;
    if (kt + 1 < nt) stage(kt + 1);   // other buffer; its readers are done

    bf16x8 bfr[4];
    #pragma unroll
    for (int ni = 0; ni < 4; ++ni) {
      const int rb = wn*64 + ni*16 + l15;
      bfr[ni] = *(const bf16x8*)(buf + 8192 + rb*64
                    + ((kgq*16) ^ ((rb & 3) << 4)));
    }
    bf16x8 af[4];
    #pragma unroll
    for (int mi = 0; mi < 4; ++mi) {
      const int ra = wm*64 + mi*16 + l15;
      af[mi] = *(const bf16x8*)(buf + ra*64
                    + ((kgq*16) ^ ((ra & 3) << 4)));
    }
    __builtin_amdgcn_s_setprio(1);
    #pragma unroll
    for (int mi = 0; mi < 4; ++mi)
      #pragma unroll
      for (int ni = 0; ni < 4; ++ni)
        acc[mi][ni] = MF(af[mi], bfr[ni], acc[mi][ni]);
    __builtin_amdgcn_s_setprio(0);
  }

  // epilogue: C/D layout col = l15, row = (lane>>4)*4 + j
  const int cr = (lane >> 4) << 2;
  #pragma unroll
  for (int mi = 0; mi < 4; ++mi) {
    #pragma unroll
    for (int ni = 0; ni < 4; ++ni) {
      const int col = col0 + wn*64 + ni*16 + l15;
      #pragma unroll
      for (int j = 0; j < 4; ++j) {
        const int row = row0 + wm*64 + mi*16 + cr + j;
        const float v = acc[mi][ni][j];
        if (EPI == 1) {
          ((float*)Cout + (size_t)bz*cSlice)[(size_t)row * Nw + col] = v + bias[col];
        } else {
          ((__bf16*)Cout + (size_t)bz*cSlice)[(size_t)row * Nw + col] = (__bf16)v;
        }
      }
    }
  }
}

// ---- combined log-weights: Baug rows 768..1151 = scale * (w @ qkv_w_side) --
__global__ __launch_bounds__(256) void wlog_kernel(
    const float* __restrict__ qkv_w, const float* __restrict__ w,
    __bf16* __restrict__ Baug) {
  const int idx = blockIdx.x * 256 + threadIdx.x;   // 2*192*384
  if (idx >= 2*192*384) return;
  const int d = idx % 384, rs = idx / 384;
  const int side = rs / 192, hm = rs % 192;
  const int h = hm / 24;
  const float* wr = w + (size_t)hm * 48;
  const float* qw = qkv_w + ((size_t)(side*384 + h*48)) * 384 + d;
  float acc = 0.f;
  #pragma unroll
  for (int c = 0; c < 48; ++c)
    acc += wr[c] * qw[(size_t)c * 384];
  Baug[(size_t)(768 + side*192 + hm) * 384 + d] = (__bf16)(acc * SCALE);
}

// ---------------- ktv fused: phi_k from [k|lk], MFMA ktv + ksum ----------
__global__ __launch_bounds__(256) void ktv_fused(
    const __bf16* __restrict__ kvll, float* __restrict__ ktv_f,
    float* __restrict__ ksum) {
  const int b = blockIdx.z, h = blockIdx.y, sp = blockIdx.x;
  const int t = threadIdx.x, wv = t >> 6, lane = t & 63;
  const int l15 = lane & 15, g = lane >> 4;
  const int bh = b*H_SZ + h;
  __shared__ __align__(16) __bf16 vT[4][48][40];    // [wave][c][tok]
  __shared__ __align__(16) __bf16 phiT[4][24][40];  // [wave][m][tok]
  __shared__ float red[4][1152];
  f32x4 acc[2][3] = {};
  f32x4 aks[2] = {};                 // ksum via ones-column MFMA
  const int nbase = sp*512 + wv*128;

  bf16x8 ones{};                     // B-frag: col 0 = all-ones
  if (l15 == 0)
    #pragma unroll
    for (int j = 0; j < 8; ++j) ones[j] = (__bf16)1.0f;

  for (int step = 0; step < 4; ++step) {
    const int n0 = nbase + step*32;
    #pragma unroll
    for (int it = 0; it < 3; ++it) {
      const int task = it*64 + lane;
      const int tk = task / 6, p = task % 6;
      const short8 r = *(const short8*)(kvll + ((size_t)(b*N_SZ) + n0 + tk)*1152
                                            + 384 + h*C_SZ + p*8);
      #pragma unroll
      for (int e = 0; e < 8; ++e)
        vT[wv][p*8 + e][tk] = __builtin_bit_cast(__bf16, (short)r[e]);
    }
    if (lane < 32) {
      const __bf16* row = kvll + ((size_t)(b*N_SZ) + n0 + lane)*1152 + h*C_SZ;
      float ss = 0.f;
      #pragma unroll
      for (int i = 0; i < 6; ++i) {
        const short8 r = *(const short8*)(row + i*8);
        #pragma unroll
        for (int j = 0; j < 8; ++j) { const float f = bf2f(r[j]) * SCALE; ss += f*f; }
      }
      const float hs = 0.5f * ss;
      const __bf16* lk = kvll + ((size_t)(b*N_SZ) + n0 + lane)*1152 + 960 + h*24;
      #pragma unroll
      for (int i = 0; i < 3; ++i) {
        const short8 r = *(const short8*)(lk + i*8);
        #pragma unroll
        for (int j = 0; j < 8; ++j)
          phiT[wv][i*8 + j][lane] = (__bf16)(__expf(bf2f(r[j]) - hs) * RSM);
      }
    }
    const bf16x8 a0 = *(const bf16x8*)(&phiT[wv][l15][g*8]);
    bf16x8 a1{};
    if (l15 < 8) a1 = *(const bf16x8*)(&phiT[wv][16 + l15][g*8]);
    #pragma unroll
    for (int ct = 0; ct < 3; ++ct) {
      const bf16x8 bfr = *(const bf16x8*)(&vT[wv][ct*16 + l15][g*8]);
      acc[0][ct] = MF(a0, bfr, acc[0][ct]);
      acc[1][ct] = MF(a1, bfr, acc[1][ct]);
    }
    aks[0] = MF(a0, ones, aks[0]);
    aks[1] = MF(a1, ones, aks[1]);
  }

  if (l15 == 0) {
    #pragma unroll
    for (int mt = 0; mt < 2; ++mt)
      #pragma unroll
      for (int jj = 0; jj < 4; ++jj) {
        const int m = mt*16 + g*4 + jj;
        if (m < 24) atomicAdd(&ksum[bh*24 + m], aks[mt][jj]);
      }
  }
  #pragma unroll
  for (int mt = 0; mt < 2; ++mt)
    #pragma unroll
    for (int ct = 0; ct < 3; ++ct)
      #pragma unroll
      for (int jj = 0; jj < 4; ++jj) {
        const int row = mt*16 + g*4 + jj;
        if (row < 24)
          red[wv][row*48 + ct*16 + l15] = acc[mt][ct][jj];
      }
  __syncthreads();
  for (int i = t; i < 1152; i += 256) {
    const float s = red[0][i] + red[1][i] + red[2][i] + red[3][i];
    atomicAdd(&ktv_f[bh*1152 + i], s);
  }
}

// ---- Gt[b][o][hm] = sum_c ktv[bh][m][c] * proj_w[o][48h+c]  (bf16 out) ----
__global__ __launch_bounds__(256) void gt_kernel(
    const float* __restrict__ ktv_f, const float* __restrict__ proj_w,
    __bf16* __restrict__ Gt) {
  const int idx = blockIdx.x * 256 + threadIdx.x;   // 4*384*192
  if (idx >= 4*384*192) return;
  const int hm = idx % 192, o = (idx / 192) % 384, b = idx / (192*384);
  const int h = hm / 24, m = hm % 24;
  const float* kt = ktv_f + ((size_t)(b*H_SZ + h))*1152 + m*48;
  const float* pw = proj_w + (size_t)o*384 + h*48;
  float acc = 0.f;
  #pragma unroll
  for (int c = 0; c < 48; ++c) acc += kt[c] * pw[c];
  Gt[((size_t)b*384 + o)*192 + hm] = (__bf16)acc;
}

// ---- P'[n][hm] = phi_q / D_h  (phi_q = exp(lq)*RSM; hs_q cancels) --------
__global__ __launch_bounds__(256) void pprime_kernel(
    const __bf16* __restrict__ kvll, const float* __restrict__ ksum,
    __bf16* __restrict__ Pp) {
  const int tok = blockIdx.x * 256 + threadIdx.x;
  const int b = (blockIdx.x * 256) >> 14;
  __shared__ float ksl[192];
  if (threadIdx.x < 192) ksl[threadIdx.x] = ksum[b*192 + threadIdx.x];
  __syncthreads();

  const __bf16* lq = kvll + (size_t)tok*1152 + 768;
  __bf16* po = Pp + (size_t)tok*192;
  #pragma unroll
  for (int h = 0; h < 8; ++h) {
    float ph[24];
    float d = EPS_V;
    #pragma unroll
    for (int i = 0; i < 3; ++i) {
      const short8 r = *(const short8*)(lq + h*24 + i*8);
      #pragma unroll
      for (int j = 0; j < 8; ++j) {
        const float p = __expf(bf2f(r[j])) * RSM;
        ph[i*8 + j] = p;
        d += p * ksl[h*24 + i*8 + j];
      }
    }
    const float inv = 1.0f / d;
    #pragma unroll
    for (int i = 0; i < 3; ++i) {
      short8 pk;
      #pragma unroll
      for (int j = 0; j < 8; ++j) pk[j] = f2bf_s(ph[i*8 + j] * inv);
      *(short8*)(po + h*24 + i*8) = pk;
    }
  }
}

// ---------------- fp32 -> bf16 convert ----------------
__global__ __launch_bounds__(256) void f32_to_bf16_kernel(
    const float* __restrict__ in, __bf16* __restrict__ out, int n8) {
  const int i = blockIdx.x * blockDim.x + threadIdx.x;
  if (i >= n8) return;
  const f32x4v a = *(const f32x4v*)(in + (size_t)i*8);
  const f32x4v c = *(const f32x4v*)(in + (size_t)i*8 + 4);
  short8 pk;
  #pragma unroll
  for (int j = 0; j < 4; ++j) {
    pk[j]     = f2bf_s(a[j]);
    pk[4 + j] = f2bf_s(c[j]);
  }
  *(short8*)(out + (size_t)i*8) = pk;
}

extern "C" void kernel_launch(void* const* d_in, const int* in_sizes, int n_in,
                              void* d_out, int out_size, void* d_ws, size_t ws_size,
                              hipStream_t stream) {
  (void)in_sizes; (void)n_in; (void)out_size; (void)ws_size;
  const float* x      = (const float*)d_in[0];
  const float* qkv_w  = (const float*)d_in[1];
  const float* proj_w = (const float*)d_in[2];
  const float* proj_b = (const float*)d_in[3];
  const float* w      = (const float*)d_in[4];
  float* out = (float*)d_out;

  const size_t BN_TOT = (size_t)B_SZ * N_SZ;           // 65536
  char* ws = (char*)d_ws;
  size_t off = 0;
  auto alloc = [&](size_t bytes) {
    char* p = ws + off;
    off += (bytes + 255) & ~(size_t)255;
    return p;
  };
  __bf16* x_bf  = (__bf16*)alloc(BN_TOT * DIM_SZ * 2);          // 50.3 MB
  __bf16* Baug  = (__bf16*)alloc((size_t)1152 * 384 * 2);       // 0.88 MB
  __bf16* kvll  = (__bf16*)alloc(BN_TOT * 1152 * 2);            // 151 MB
  float*  ktv_f = (float*)alloc((size_t)32 * 1152 * 4);
  float*  ksum  = (float*)alloc((size_t)32 * 24 * 4);
  __bf16* Pp    = (__bf16*)alloc(BN_TOT * 192 * 2);             // 25.2 MB
  __bf16* Gt    = (__bf16*)alloc((size_t)B_SZ * 384 * 192 * 2); // 0.6 MB

  hipMemsetAsync(ktv_f, 0, (size_t)32 * 1152 * 4, stream);
  hipMemsetAsync(ksum,  0, (size_t)32 * 24 * 4, stream);

  static const int LDS32 = 2 * 16384;    // 32 KB
  hipFuncSetAttribute(reinterpret_cast<const void*>(&gemm32<0>),
                      hipFuncAttributeMaxDynamicSharedMemorySize, LDS32);
  hipFuncSetAttribute(reinterpret_cast<const void*>(&gemm32<1>),
                      hipFuncAttributeMaxDynamicSharedMemorySize, LDS32);

  // conversions + combined weights
  {
    const int n8x = (int)(BN_TOT * DIM_SZ / 8);
    f32_to_bf16_kernel<<<(n8x + 255)/256, 256, 0, stream>>>(x, x_bf, n8x);
    // Baug rows 0..767 = [Wk | Wv] (qkv_w rows 384..1151)
    const int n8kv = 768 * 384 / 8;
    f32_to_bf16_kernel<<<(n8kv + 255)/256, 256, 0, stream>>>(
        qkv_w + (size_t)384 * 384, Baug, n8kv);
    // Baug rows 768..1151 = scale * (w @ qkv_w_{q,k})
    wlog_kernel<<<(2*192*384 + 255)/256, 256, 0, stream>>>(qkv_w, w, Baug);
  }

  // kvll = x @ Baug.T : [k | v | lq | lk]   (65536 x 1152 x 384)
  gemm32<0><<<dim3(1152/128, BN_TOT/128, 1), 256, LDS32, stream>>>(
      x_bf, Baug, kvll, nullptr, (int)BN_TOT, 1152, DIM_SZ, 0, 0, 0);

  // ktv + ksum (phi_k from k + lk)
  ktv_fused<<<dim3(32, H_SZ, B_SZ), 256, 0, stream>>>(kvll, ktv_f, ksum);

  // Gt = ktv @ proj_w^T (per batch), P' = phi_q / D
  gt_kernel<<<(4*384*192 + 255)/256, 256, 0, stream>>>(ktv_f, proj_w, Gt);
  pprime_kernel<<<(int)(BN_TOT/256), 256, 0, stream>>>(kvll, ksum, Pp);

  // out = P' @ Gt^T + bias   (4 x [16384 x 384 x 192])
  gemm32<1><<<dim3(384/128, N_SZ/128, B_SZ), 256, LDS32, stream>>>(
      Pp, Gt, out, proj_b, N_SZ, 384, 192,
      (size_t)N_SZ * 192, (size_t)384 * 192, (size_t)N_SZ * 384);
}